// Round 2
// baseline (4358.606 us; speedup 1.0000x reference)
//
#include <hip/hip_runtime.h>

// Sinkhorn: B=256, N=512, 50 iters, REG=1.
//   k_sinkhorn: one 1024-thread block per batch; K generated on the fly in
//     sweep 0 (bf16(exp(-cost))) and kept resident: 13 rows/wave in VGPRs
//     (52 VGPR), 7 rows/wave in LDS (112 KB), 12 rows/wave streamed via the
//     K region in d_out (49 MB total, L3-resident after sweep 0).
//     Fused sweeps: per row pair, dot with v -> pair-packed butterfly
//     (1 pack + 5 shared steps) -> u via rcp -> readlane broadcast ->
//     column accumulate. 2 barriers/sweep.
//   k_out: out[b,i,j] = log u[b,i] - cost[b,i,j] + log v[b,j].

#define SK_B    256
#define SK_N    512
#define SK_NIT  50
#define SK_RREG 13    // rows r in [0,13) per wave: VGPR-resident (52 VGPRs)
#define SK_GST  20    // rows r in [13,20) per wave: LDS (112 rows, 112 KB); r>=20 streamed

__device__ __forceinline__ float bf_lo(unsigned int u) {
    union { unsigned int u; float f; } x; x.u = u << 16; return x.f;
}
__device__ __forceinline__ float bf_hi(unsigned int u) {
    union { unsigned int u; float f; } x; x.u = u & 0xffff0000u; return x.f;
}
__device__ __forceinline__ unsigned int pk2bf(float a, float b) {
    union { float f; unsigned int u; } x, y; x.f = a; y.f = b;
    unsigned int ra = (x.u + 0x7FFFu + ((x.u >> 16) & 1u)) >> 16;
    unsigned int rb = (y.u + 0x7FFFu + ((y.u >> 16) & 1u)) & 0xFFFF0000u;
    return ra | rb;
}
__device__ __forceinline__ float rdlane(float v, int l) {
    return __uint_as_float(__builtin_amdgcn_readlane(__float_as_uint(v), l));
}

// unpack 8 bf16 cols (cols lane*8 .. lane*8+7) with caller-chosen names
#define SK_UNP(p, n0,n1,n2,n3,n4,n5,n6,n7) \
    const float n0 = bf_lo((p).x), n1 = bf_hi((p).x), n2 = bf_lo((p).y), n3 = bf_hi((p).y), \
                n4 = bf_lo((p).z), n5 = bf_hi((p).z), n6 = bf_lo((p).w), n7 = bf_hi((p).w)

#define SK_DOT(s, n0,n1,n2,n3,n4,n5,n6,n7) \
    float s; { \
        float e_ = n0 * vv0; e_ = fmaf(n2, vv2, e_); e_ = fmaf(n4, vv4, e_); e_ = fmaf(n6, vv6, e_); \
        float o_ = n1 * vv1; o_ = fmaf(n3, vv3, o_); o_ = fmaf(n5, vv5, o_); o_ = fmaf(n7, vv7, o_); \
        s = e_ + o_; \
    }

#define SK_LOADVV() \
    const float vv0 = v_s[lane*8+0], vv1 = v_s[lane*8+1], \
                vv2 = v_s[lane*8+2], vv3 = v_s[lane*8+3], \
                vv4 = v_s[lane*8+4], vv5 = v_s[lane*8+5], \
                vv6 = v_s[lane*8+6], vv7 = v_s[lane*8+7]

// fetch packed row r (unrolled constant r) into p from reg/LDS/stream buffers
#define SK_FETCH(p, r, pfreg) \
    uint4 p; \
    if ((r) < SK_RREG)     p = kreg[(r)]; \
    else if ((r) < SK_GST) p = Kl[(((r) - SK_RREG) * 16 + w) * 64 + lane]; \
    else                   p = pfreg;

// pair-packed butterfly: sA,sB (per-lane partials of rows r0,r1) -> xx,
// where lane l ends with full rowsum of row (l&1) in ALL lanes.
#define SK_RED2(xx, sA, sB) \
    float xx; { \
        float x_ = (lane & 1) ? sB : sA; \
        float y_ = (lane & 1) ? sA : sB; \
        x_ += __shfl_xor(y_, 1, 64); \
        x_ += __shfl_xor(x_, 2, 64); \
        x_ += __shfl_xor(x_, 4, 64); \
        x_ += __shfl_xor(x_, 8, 64); \
        x_ += __shfl_xor(x_, 16, 64); \
        x_ += __shfl_xor(x_, 32, 64); \
        xx = x_; \
    }

__launch_bounds__(1024)
__global__ void k_sinkhorn(const float* __restrict__ cost,
                           unsigned short* __restrict__ Kg,
                           float* __restrict__ lu, float* __restrict__ lv) {
    const int b = blockIdx.x;
    const float4* __restrict__ costb = (const float4*)(cost + (size_t)b * SK_N * SK_N);
    uint4* __restrict__ Kb = (uint4*)(Kg + (size_t)b * SK_N * SK_N);
    __shared__ uint4 Kl[(SK_GST - SK_RREG) * 16 * 64];  // 112 KB
    __shared__ float part[16][SK_N];                    //  32 KB
    __shared__ float v_s[SK_N];                         //   2 KB
    const int tid  = threadIdx.x;
    const int lane = tid & 63;
    const int w    = tid >> 6;

    uint4 kreg[SK_RREG];   // static-indexed only (loops fully unrolled)

    // ---- sweep 0: K = bf16(exp(-cost)) on the fly; stash rows to regs/LDS/
    //      global (streamed rows only); accumulate column sums with u0 = 1/N.
    {
        float a0=0.f,a1=0.f,a2=0.f,a3=0.f,a4=0.f,a5=0.f,a6=0.f,a7=0.f;
        #pragma unroll
        for (int r = 0; r < 32; ++r) {
            const int i = w + 16 * r;
            const float4 c0 = costb[i * 128 + 2 * lane];
            const float4 c1 = costb[i * 128 + 2 * lane + 1];
            uint4 kp;
            kp.x = pk2bf(__expf(-c0.x), __expf(-c0.y));
            kp.y = pk2bf(__expf(-c0.z), __expf(-c0.w));
            kp.z = pk2bf(__expf(-c1.x), __expf(-c1.y));
            kp.w = pk2bf(__expf(-c1.z), __expf(-c1.w));
            if (r < SK_RREG)     kreg[r] = kp;
            else if (r < SK_GST) Kl[((r - SK_RREG) * 16 + w) * 64 + lane] = kp;
            else                 Kb[i * 64 + lane] = kp;
            SK_UNP(kp, k0,k1,k2,k3,k4,k5,k6,k7);
            a0+=k0; a1+=k1; a2+=k2; a3+=k3; a4+=k4; a5+=k5; a6+=k6; a7+=k7;
        }
        float* pr = &part[w][lane * 8];
        pr[0]=a0; pr[1]=a1; pr[2]=a2; pr[3]=a3; pr[4]=a4; pr[5]=a5; pr[6]=a6; pr[7]=a7;
        __syncthreads();
        if (tid < SK_N) {
            float t0 = part[0][tid] + part[1][tid],   t1 = part[2][tid] + part[3][tid];
            float t2 = part[4][tid] + part[5][tid],   t3 = part[6][tid] + part[7][tid];
            float t4 = part[8][tid] + part[9][tid],   t5 = part[10][tid] + part[11][tid];
            float t6 = part[12][tid] + part[13][tid], t7 = part[14][tid] + part[15][tid];
            float s = ((t0+t1)+(t2+t3)) + ((t4+t5)+(t6+t7));
            v_s[tid] = __builtin_amdgcn_rcpf(s * (1.0f / SK_N));   // v1
        }
        __syncthreads();
    }

    // ---- fused sweeps t = 1..49: u_t = 1/(K v_t) per row pair, column sums
    //      accumulate u_t,i * K_ij -> v_{t+1}. One resident/streamed K pass.
    for (int t = 1; t < SK_NIT; ++t) {
        SK_LOADVV();
        float a0=0.f,a1=0.f,a2=0.f,a3=0.f,a4=0.f,a5=0.f,a6=0.f,a7=0.f;
        uint4 pfa = Kb[(w + 16 * SK_GST) * 64 + lane];
        uint4 pfb = Kb[(w + 16 * (SK_GST + 1)) * 64 + lane];
        #pragma unroll
        for (int g = 0; g < 16; ++g) {
            const int r0 = 2 * g, r1 = r0 + 1;
            SK_FETCH(p0, r0, pfa);
            SK_FETCH(p1, r1, pfb);
            if (r0 >= SK_GST && r0 + 2 < 32) {       // depth-1 group prefetch
                pfa = Kb[(w + 16 * (r0 + 2)) * 64 + lane];
                pfb = Kb[(w + 16 * (r1 + 2)) * 64 + lane];
            }
            SK_UNP(p0, A0,A1,A2,A3,A4,A5,A6,A7);
            SK_UNP(p1, B0,B1,B2,B3,B4,B5,B6,B7);
            SK_DOT(sA, A0,A1,A2,A3,A4,A5,A6,A7);
            SK_DOT(sB, B0,B1,B2,B3,B4,B5,B6,B7);
            SK_RED2(xx, sA, sB);
            const float uu = __builtin_amdgcn_rcpf(xx);
            const float uA = rdlane(uu, 0);
            const float uB = rdlane(uu, 1);
            a0 = fmaf(uA, A0, fmaf(uB, B0, a0));
            a1 = fmaf(uA, A1, fmaf(uB, B1, a1));
            a2 = fmaf(uA, A2, fmaf(uB, B2, a2));
            a3 = fmaf(uA, A3, fmaf(uB, B3, a3));
            a4 = fmaf(uA, A4, fmaf(uB, B4, a4));
            a5 = fmaf(uA, A5, fmaf(uB, B5, a5));
            a6 = fmaf(uA, A6, fmaf(uB, B6, a6));
            a7 = fmaf(uA, A7, fmaf(uB, B7, a7));
        }
        float* pr = &part[w][lane * 8];
        pr[0]=a0; pr[1]=a1; pr[2]=a2; pr[3]=a3; pr[4]=a4; pr[5]=a5; pr[6]=a6; pr[7]=a7;
        __syncthreads();
        if (tid < SK_N) {
            float t0 = part[0][tid] + part[1][tid],   t1 = part[2][tid] + part[3][tid];
            float t2 = part[4][tid] + part[5][tid],   t3 = part[6][tid] + part[7][tid];
            float t4 = part[8][tid] + part[9][tid],   t5 = part[10][tid] + part[11][tid];
            float t6 = part[12][tid] + part[13][tid], t7 = part[14][tid] + part[15][tid];
            float s = ((t0+t1)+(t2+t3)) + ((t4+t5)+(t6+t7));
            v_s[tid] = __builtin_amdgcn_rcpf(s);
        }
        __syncthreads();
    }

    // ---- final half-sweep: u50 = 1/(K v50); write log u, log v.
    {
        SK_LOADVV();
        uint4 pfa = Kb[(w + 16 * SK_GST) * 64 + lane];
        uint4 pfb = Kb[(w + 16 * (SK_GST + 1)) * 64 + lane];
        #pragma unroll
        for (int g = 0; g < 16; ++g) {
            const int r0 = 2 * g, r1 = r0 + 1;
            SK_FETCH(p0, r0, pfa);
            SK_FETCH(p1, r1, pfb);
            if (r0 >= SK_GST && r0 + 2 < 32) {
                pfa = Kb[(w + 16 * (r0 + 2)) * 64 + lane];
                pfb = Kb[(w + 16 * (r1 + 2)) * 64 + lane];
            }
            SK_UNP(p0, A0,A1,A2,A3,A4,A5,A6,A7);
            SK_UNP(p1, B0,B1,B2,B3,B4,B5,B6,B7);
            SK_DOT(sA, A0,A1,A2,A3,A4,A5,A6,A7);
            SK_DOT(sB, B0,B1,B2,B3,B4,B5,B6,B7);
            SK_RED2(xx, sA, sB);
            if (lane < 2)    // lane l holds rowsum of row r0+l
                lu[b * SK_N + w + 16 * (r0 + lane)] = -__logf(xx);
        }
        if (tid < SK_N) lv[b * SK_N + tid] = __logf(v_s[tid]);
    }
}

__global__ void k_out(const float4* __restrict__ cost, const float* __restrict__ lu,
                      const float4* __restrict__ lv4, float4* __restrict__ out, int n4) {
    int idx = blockIdx.x * blockDim.x + threadIdx.x;
    if (idx >= n4) return;
    int bb  = idx >> 16;            // element e = idx*4; b = e>>18
    int row = (idx >> 7) & (SK_N - 1);
    int j4  = idx & 127;
    float  l_u = lu[bb * SK_N + row];
    float4 lvv = lv4[bb * 128 + j4];
    float4 c   = cost[idx];
    float4 o;
    o.x = l_u - c.x + lvv.x;
    o.y = l_u - c.y + lvv.y;
    o.z = l_u - c.z + lvv.z;
    o.w = l_u - c.w + lvv.w;
    out[idx] = o;
}

extern "C" void kernel_launch(void* const* d_in, const int* in_sizes, int n_in,
                              void* d_out, int out_size, void* d_ws, size_t ws_size,
                              hipStream_t stream) {
    const float* cost = (const float*)d_in[0];
    float* out = (float*)d_out;

    // Streamed K rows live in the first 128 MB of d_out (bf16 layout
    // [256][512][512]); only rows r>=20 per wave are ever written/read there.
    // The epilogue overwrites d_out after k_sinkhorn completes.
    unsigned short* K = (unsigned short*)d_out;
    float* lu = (float*)d_ws;                 // 256*512 floats = 512 KB
    float* lv = lu + SK_B * SK_N;             // 512 KB

    const int n4 = SK_B * SK_N * SK_N / 4;    // 16,777,216 float4 groups

    k_sinkhorn<<<SK_B, 1024, 0, stream>>>(cost, K, lu, lv);
    k_out<<<n4 / 256, 256, 0, stream>>>((const float4*)cost, lu,
                                        (const float4*)lv, (float4*)out, n4);
}